// Round 18
// baseline (312.379 us; speedup 1.0000x reference)
//
#include <hip/hip_runtime.h>
#include <hip/hip_fp16.h>

#define NDIM 384
#define NN   147456    // 384*384
#define CZC  128

typedef _Float16 f16x8 __attribute__((ext_vector_type(8)));
typedef float    f32x4 __attribute__((ext_vector_type(4)));

static __device__ __forceinline__ unsigned short f2h(float f) {
  return __builtin_bit_cast(unsigned short, __float2half(f));
}
static __device__ __forceinline__ float h2f(unsigned short s) {
  return __half2float(__builtin_bit_cast(__half, s));
}
static __device__ __forceinline__ unsigned pk2(float lo, float hi) {
  return (unsigned)f2h(lo) | ((unsigned)f2h(hi) << 16);
}
// fast sigmoid: v_exp + v_rcp (1 ulp)
static __device__ __forceinline__ float sigmoidf_(float x) {
  return __builtin_amdgcn_rcpf(1.0f + __expf(-x));
}

// A/B/G strip layout: X[(i*128 + c)*384 + k]  (i = pair-row, c = channel, k = pair-col)

// ---------------------------------------------------------------- k0: weights fp32 -> fp16
__global__ void k0_conv(const float* __restrict__ g1, const float* __restrict__ l1,
                        const float* __restrict__ g2, const float* __restrict__ l2,
                        const float* __restrict__ gw, const float* __restrict__ ow,
                        unsigned short* __restrict__ Wh)
{
  const int m = blockIdx.x >> 6;
  const float* s = (m == 0) ? g1 : (m == 1) ? l1 : (m == 2) ? g2 : (m == 3) ? l2
                 : (m == 4) ? gw : ow;
  const int e = (blockIdx.x & 63) * 256 + threadIdx.x;
  Wh[m * 16384 + e] = f2h(s[e]);
}

// ---------------------------------------------------------------- k1: LN + A/B/G projections
// 256 thr, 128 pts/block, grid 1152. Direct strip-layout stores from the MFMA epilogue
// (acc regs 0..3 = 4 consecutive k -> one 8B store). No store-stage LDS, ONE barrier total.
// LDS 32KB -> 4 blocks/CU (vs 2): tests the latency/occupancy theory for k1's 39us/block.
__global__ __launch_bounds__(256, 4) void k1_proj(
    const float* __restrict__ pair, const float* __restrict__ lnw, const float* __restrict__ lnb,
    const unsigned short* __restrict__ Wh,
    const float* __restrict__ g1b, const float* __restrict__ l1b,
    const float* __restrict__ g2b, const float* __restrict__ l2b,
    const float* __restrict__ gtb,
    unsigned short* __restrict__ Ah, unsigned short* __restrict__ Bh,
    unsigned short* __restrict__ G)     // may be null (ws too small)
{
  __shared__ char zb[32768];   // z fp16 [128 rows][128c], 256B/row, 16B-granule XOR (row&7)
  const int t   = threadIdx.x;
  const int xcd = blockIdx.x & 7;
  const int r0  = (xcd * 144 + (blockIdx.x >> 3)) * 128;  // XCD-contiguous point ranges
  const int irow = r0 / NDIM;          // fixed pair-row for this block
  const int kk0  = r0 % NDIM;          // k-third: 0 / 128 / 256

  { // ---- load + LN -> z fp16 in LDS (4 lanes per row, 2 batches of 64 rows)
    const int rl = t >> 2, quad = t & 3, c0 = quad * 32;
    for (int b = 0; b < 2; ++b) {
      const int row = b * 64 + rl;
      const float4* src = reinterpret_cast<const float4*>(pair + (size_t)(r0 + row) * CZC + c0);
      float v[32];
      float s = 0.f, ss = 0.f;
#pragma unroll
      for (int q = 0; q < 8; ++q) {
        float4 f4 = src[q];
        v[4*q] = f4.x; v[4*q+1] = f4.y; v[4*q+2] = f4.z; v[4*q+3] = f4.w;
      }
#pragma unroll
      for (int j = 0; j < 32; ++j) { s += v[j]; ss += v[j] * v[j]; }
      s  += __shfl_xor(s, 1);  s  += __shfl_xor(s, 2);
      ss += __shfl_xor(ss, 1); ss += __shfl_xor(ss, 2);
      const float mu   = s * (1.f / 128.f);
      const float rstd = rsqrtf(ss * (1.f / 128.f) - mu * mu + 1e-5f);
      unsigned u[16];
#pragma unroll
      for (int q = 0; q < 8; ++q) {
        float4 w4 = reinterpret_cast<const float4*>(lnw + c0)[q];
        float4 b4 = reinterpret_cast<const float4*>(lnb + c0)[q];
        float z0 = (v[4*q  ] - mu) * rstd * w4.x + b4.x;
        float z1 = (v[4*q+1] - mu) * rstd * w4.y + b4.y;
        float z2 = (v[4*q+2] - mu) * rstd * w4.z + b4.z;
        float z3 = (v[4*q+3] - mu) * rstd * w4.w + b4.w;
        u[2*q] = pk2(z0, z1); u[2*q+1] = pk2(z2, z3);
      }
#pragma unroll
      for (int g = 0; g < 4; ++g) {
        int gi = quad * 4 + g;
        *reinterpret_cast<uint4*>(zb + row * 256 + 16 * (gi ^ (row & 7))) =
            make_uint4(u[4*g], u[4*g+1], u[4*g+2], u[4*g+3]);
      }
    }
  }
  __syncthreads();                     // the only barrier: zb is read-only below

  const int w = t >> 6, l = t & 63;
  const int lrow = l & 15, lk = l >> 4;
  const int colbase = w * 32;

  auto ldA = [&](int h, int mt, int ks) -> f16x8 {
    int row = h * 64 + mt * 16 + lrow;
    int gi  = ks * 4 + lk;
    return *reinterpret_cast<const f16x8*>(zb + row * 256 + 16 * (gi ^ (row & 7)));
  };
  auto ldB = [&](const unsigned short* Wm, int nt, int ks) -> f16x8 {
    int col = colbase + nt * 16 + lrow;
    return *reinterpret_cast<const f16x8*>(Wm + col * 128 + ks * 32 + lk * 8);
  };

  auto do_pair = [&](const unsigned short* Wg, const unsigned short* Wl,
                     const float* bgp, const float* blp, unsigned short* Ot) {
    unsigned short* base = Ot + (size_t)irow * 128 * NDIM + kk0;
#pragma unroll
    for (int h = 0; h < 2; ++h) {
      f32x4 accg[4][2], accl[4][2];
#pragma unroll
      for (int mt = 0; mt < 4; ++mt)
#pragma unroll
        for (int nt = 0; nt < 2; ++nt) { accg[mt][nt] = 0.f; accl[mt][nt] = 0.f; }
#pragma unroll
      for (int ks = 0; ks < 4; ++ks) {
        f16x8 af[4];
#pragma unroll
        for (int mt = 0; mt < 4; ++mt) af[mt] = ldA(h, mt, ks);
#pragma unroll
        for (int nt = 0; nt < 2; ++nt) {
          f16x8 bg_ = ldB(Wg, nt, ks);
#pragma unroll
          for (int mt = 0; mt < 4; ++mt)
            accg[mt][nt] = __builtin_amdgcn_mfma_f32_16x16x32_f16(af[mt], bg_, accg[mt][nt], 0, 0, 0);
          f16x8 bl_ = ldB(Wl, nt, ks);
#pragma unroll
          for (int mt = 0; mt < 4; ++mt)
            accl[mt][nt] = __builtin_amdgcn_mfma_f32_16x16x32_f16(af[mt], bl_, accl[mt][nt], 0, 0, 0);
        }
      }
#pragma unroll
      for (int mt = 0; mt < 4; ++mt)
#pragma unroll
        for (int nt = 0; nt < 2; ++nt) {
          int col = colbase + nt * 16 + lrow;
          float gb = bgp[col], lb = blp[col];
          float a0 = sigmoidf_(accg[mt][nt][0] + gb) * (accl[mt][nt][0] + lb);
          float a1 = sigmoidf_(accg[mt][nt][1] + gb) * (accl[mt][nt][1] + lb);
          float a2 = sigmoidf_(accg[mt][nt][2] + gb) * (accl[mt][nt][2] + lb);
          float a3 = sigmoidf_(accg[mt][nt][3] + gb) * (accl[mt][nt][3] + lb);
          *reinterpret_cast<uint2*>(base + (size_t)col * NDIM + h * 64 + mt * 16 + lk * 4)
              = make_uint2(pk2(a0, a1), pk2(a2, a3));
        }
    }
  };

  do_pair(Wh + 0 * 16384, Wh + 1 * 16384, g1b, l1b, Ah);
  do_pair(Wh + 2 * 16384, Wh + 3 * 16384, g2b, l2b, Bh);

  if (G) {  // gate -> G strip-layout
    unsigned short* base = G + (size_t)irow * 128 * NDIM + kk0;
    const unsigned short* Wg = Wh + 4 * 16384;
#pragma unroll
    for (int h = 0; h < 2; ++h) {
      f32x4 acc[4][2];
#pragma unroll
      for (int mt = 0; mt < 4; ++mt)
#pragma unroll
        for (int nt = 0; nt < 2; ++nt) acc[mt][nt] = 0.f;
#pragma unroll
      for (int ks = 0; ks < 4; ++ks) {
        f16x8 af[4];
#pragma unroll
        for (int mt = 0; mt < 4; ++mt) af[mt] = ldA(h, mt, ks);
#pragma unroll
        for (int nt = 0; nt < 2; ++nt) {
          f16x8 bf_ = ldB(Wg, nt, ks);
#pragma unroll
          for (int mt = 0; mt < 4; ++mt)
            acc[mt][nt] = __builtin_amdgcn_mfma_f32_16x16x32_f16(af[mt], bf_, acc[mt][nt], 0, 0, 0);
        }
      }
#pragma unroll
      for (int mt = 0; mt < 4; ++mt)
#pragma unroll
        for (int nt = 0; nt < 2; ++nt) {
          int col = colbase + nt * 16 + lrow;
          float gb = gtb[col];
          *reinterpret_cast<uint2*>(base + (size_t)col * NDIM + h * 64 + mt * 16 + lk * 4)
              = make_uint2(pk2(sigmoidf_(acc[mt][nt][0] + gb), sigmoidf_(acc[mt][nt][1] + gb)),
                           pk2(sigmoidf_(acc[mt][nt][2] + gb), sigmoidf_(acc[mt][nt][3] + gb)));
        }
    }
  }
}

// ---------------------------------------------------------------- k2: per-channel NT GEMM
// V16[c][i][j] = sum_k A[i][c][k]*B[j][c][k] (strip layout inputs). 128x128 tile, BK=32.
__global__ __launch_bounds__(256) void k2_tri(
    const unsigned short* __restrict__ Ah, const unsigned short* __restrict__ Bh,
    unsigned short* __restrict__ v16)
{
  __shared__ char As[8192];   // [128 rows][32 k] fp16, 64B/row, granule XOR (row&3)
  __shared__ char Bs[8192];
  __shared__ char Vs[32768];  // store-stage [128 i][128 j] fp16, 256B/row, 16B-slot XOR (i&15)
  const int x  = blockIdx.x & 7;
  const int r  = blockIdx.x >> 3;
  const int tt = r % 9;
  const int c  = (r / 9) * 8 + x;
  const int ib = (tt / 3) * 128, jb = (tt % 3) * 128;
  const size_t co = (size_t)c * NN;
  const int t = threadIdx.x, w = t >> 6, l = t & 63;
  const int wi = (w >> 1) * 64, wj = (w & 1) * 64;
  const int lrow = l & 15, lk = l >> 4;
  const int srow = t >> 2, sgr = t & 3;

  f32x4 acc[4][4];
#pragma unroll
  for (int mt = 0; mt < 4; ++mt)
#pragma unroll
    for (int nt = 0; nt < 4; ++nt) acc[mt][nt] = 0.f;

  for (int kb = 0; kb < 12; ++kb) {
    const int kofs = kb * 32 + sgr * 8;
    const size_t ka  = ((size_t)(ib + srow) * 128 + c) * NDIM + kofs;
    const size_t kb_ = ((size_t)(jb + srow) * 128 + c) * NDIM + kofs;
    const size_t rstep = (size_t)64 * 128 * NDIM;
    uint4 a0 = *reinterpret_cast<const uint4*>(Ah + ka);
    uint4 a1 = *reinterpret_cast<const uint4*>(Ah + ka + rstep);
    uint4 b0 = *reinterpret_cast<const uint4*>(Bh + kb_);
    uint4 b1 = *reinterpret_cast<const uint4*>(Bh + kb_ + rstep);
    __syncthreads();
    const int g0 = 16 * (sgr ^ (srow & 3));
    *reinterpret_cast<uint4*>(As + srow * 64 + g0)        = a0;
    *reinterpret_cast<uint4*>(As + (srow + 64) * 64 + g0) = a1;
    *reinterpret_cast<uint4*>(Bs + srow * 64 + g0)        = b0;
    *reinterpret_cast<uint4*>(Bs + (srow + 64) * 64 + g0) = b1;
    __syncthreads();
    f16x8 af[4], bfr[4];
#pragma unroll
    for (int mt = 0; mt < 4; ++mt) {
      int row = wi + mt * 16 + lrow;
      af[mt] = *reinterpret_cast<const f16x8*>(As + row * 64 + 16 * (lk ^ (row & 3)));
    }
#pragma unroll
    for (int nt = 0; nt < 4; ++nt) {
      int row = wj + nt * 16 + lrow;
      bfr[nt] = *reinterpret_cast<const f16x8*>(Bs + row * 64 + 16 * (lk ^ (row & 3)));
    }
#pragma unroll
    for (int mt = 0; mt < 4; ++mt)
#pragma unroll
      for (int nt = 0; nt < 4; ++nt)
        acc[mt][nt] = __builtin_amdgcn_mfma_f32_16x16x32_f16(af[mt], bfr[nt], acc[mt][nt], 0, 0, 0);
  }

  // ---- stage V tile [i][j] then coalesced 256B-row stores
  __syncthreads();
#pragma unroll
  for (int mt = 0; mt < 4; ++mt)
#pragma unroll
    for (int nt = 0; nt < 4; ++nt) {
      const int j = wj + nt * 16 + lrow;
#pragma unroll
      for (int reg = 0; reg < 4; ++reg) {
        const int i = wi + mt * 16 + lk * 4 + reg;
        int sl = (j >> 3) ^ (i & 15);
        *reinterpret_cast<unsigned short*>(Vs + i * 256 + sl * 16 + (j & 7) * 2)
            = f2h(acc[mt][nt][reg]);
      }
    }
  __syncthreads();
  unsigned short* vc = v16 + co;
#pragma unroll
  for (int q = 0; q < 8; ++q) {
    int idx = t + 256 * q;              // 2048 chunks of 16B
    int i = idx >> 4, sl = idx & 15;
    uint4 u = *reinterpret_cast<const uint4*>(Vs + i * 256 + ((sl ^ (i & 15)) * 16));
    *reinterpret_cast<uint4*>(vc + (size_t)(ib + i) * NDIM + jb + sl * 8) = u;
  }
}

// ---------------------------------------------------------------- k3g: LN(vals) @ out_w^T * G + out_b
__global__ __launch_bounds__(256, 4) void k3g(
    const unsigned short* __restrict__ v16, const unsigned short* __restrict__ G,
    const float* __restrict__ lnow, const float* __restrict__ lnob,
    const unsigned short* __restrict__ Wh, const float* __restrict__ outb,
    float* __restrict__ outp)
{
  __shared__ char smem[36864];
  unsigned short* vs = reinterpret_cast<unsigned short*>(smem);        // [128][72] fp16
  unsigned short* gs = reinterpret_cast<unsigned short*>(smem + 18432);
  char* zvb = smem;                    // overlays vs after its reads complete
  const int t  = threadIdx.x;
  const int p0 = blockIdx.x * 64;
  const int irow = p0 / NDIM;          // fixed pair-row (64 | 384)
  const int kk0  = p0 % NDIM;

  // ---- phase A: V (channel-major) + G (strip) tiles -> LDS
#pragma unroll
  for (int q = 0; q < 4; ++q) {
    int ci = t + 256 * q;
    int c = ci >> 3, ch8 = ci & 7;
    uint4 u = *reinterpret_cast<const uint4*>(v16 + (size_t)c * NN + p0 + ch8 * 8);
    int g = ch8 ^ (c & 7);
    *reinterpret_cast<uint4*>(vs + c * 72 + g * 8) = u;
  }
  {
    const unsigned short* gbase = G + (size_t)irow * 128 * NDIM + kk0;
#pragma unroll
    for (int q = 0; q < 4; ++q) {
      int ci = t + 256 * q;
      int c = ci >> 3, ch8 = ci & 7;
      uint4 u = *reinterpret_cast<const uint4*>(gbase + (size_t)c * NDIM + ch8 * 8);
      int g = ch8 ^ (c & 7);
      *reinterpret_cast<uint4*>(gs + c * 72 + g * 8) = u;
    }
  }
  __syncthreads();

  const int w = t >> 6, l = t & 63;
  const int lrow = l & 15, lk = l >> 4;
  const int colbase = w * 32;

  { // ---- phase C: per-point LN(vals) -> zvb (overlaid on vs)
    const int pl = t >> 2, quad = t & 3, c0q = quad * 32;
    float v[32];
#pragma unroll
    for (int j = 0; j < 32; ++j) {
      int c = c0q + j;
      v[j] = h2f(vs[c * 72 + (((pl >> 3) ^ (c & 7)) << 3) + (pl & 7)]);
    }
    float s = 0.f, ss = 0.f;
#pragma unroll
    for (int j = 0; j < 32; ++j) { s += v[j]; ss += v[j] * v[j]; }
    s  += __shfl_xor(s, 1);  s  += __shfl_xor(s, 2);
    ss += __shfl_xor(ss, 1); ss += __shfl_xor(ss, 2);
    const float mu   = s * (1.f / 128.f);
    const float rstd = rsqrtf(ss * (1.f / 128.f) - mu * mu + 1e-5f);
    unsigned u[16];
#pragma unroll
    for (int q = 0; q < 8; ++q) {
      float4 w4 = reinterpret_cast<const float4*>(lnow + c0q)[q];
      float4 b4 = reinterpret_cast<const float4*>(lnob + c0q)[q];
      float z0 = (v[4*q  ] - mu) * rstd * w4.x + b4.x;
      float z1 = (v[4*q+1] - mu) * rstd * w4.y + b4.y;
      float z2 = (v[4*q+2] - mu) * rstd * w4.z + b4.z;
      float z3 = (v[4*q+3] - mu) * rstd * w4.w + b4.w;
      u[2*q] = pk2(z0, z1); u[2*q+1] = pk2(z2, z3);
    }
    __syncthreads();                   // all vs reads complete before overwrite
#pragma unroll
    for (int g = 0; g < 4; ++g) {
      int gi = quad * 4 + g;
      *reinterpret_cast<uint4*>(zvb + pl * 256 + 16 * (gi ^ (pl & 7))) =
          make_uint4(u[4*g], u[4*g+1], u[4*g+2], u[4*g+3]);
    }
  }
  __syncthreads();

  // ---- phase D: out MFMA + gated epilogue
  const unsigned short* Wo = Wh + 5 * 16384;
  f32x4 acc[4][2];
#pragma unroll
  for (int mt = 0; mt < 4; ++mt)
#pragma unroll
    for (int nt = 0; nt < 2; ++nt) acc[mt][nt] = 0.f;
#pragma unroll
  for (int ks = 0; ks < 4; ++ks) {
    f16x8 af[4];
#pragma unroll
    for (int mt = 0; mt < 4; ++mt) {
      int row = mt * 16 + lrow;
      int gi  = ks * 4 + lk;
      af[mt] = *reinterpret_cast<const f16x8*>(zvb + row * 256 + 16 * (gi ^ (row & 7)));
    }
#pragma unroll
    for (int nt = 0; nt < 2; ++nt) {
      int cz = colbase + nt * 16 + lrow;
      f16x8 bf_ = *reinterpret_cast<const f16x8*>(Wo + cz * 128 + ks * 32 + lk * 8);
#pragma unroll
      for (int mt = 0; mt < 4; ++mt)
        acc[mt][nt] = __builtin_amdgcn_mfma_f32_16x16x32_f16(af[mt], bf_, acc[mt][nt], 0, 0, 0);
    }
  }
#pragma unroll
  for (int mt = 0; mt < 4; ++mt)
#pragma unroll
    for (int nt = 0; nt < 2; ++nt) {
      int cz = colbase + nt * 16 + lrow;
      float ob = outb[cz];
#pragma unroll
      for (int reg = 0; reg < 4; ++reg) {
        int plc = mt * 16 + lk * 4 + reg;
        float gv = h2f(gs[cz * 72 + (((plc >> 3) ^ (cz & 7)) << 3) + (plc & 7)]);
        outp[(size_t)(p0 + plc) * CZC + cz] = gv * (acc[mt][nt][reg] + ob);
      }
    }
}

// ---------------------------------------------------------------- k3r: recompute-gate tier (no G)
__global__ __launch_bounds__(256, 3) void k3r(
    const float* __restrict__ pair, const unsigned short* __restrict__ v16,
    const float* __restrict__ lnpw, const float* __restrict__ lnpb,
    const float* __restrict__ lnow, const float* __restrict__ lnob,
    const unsigned short* __restrict__ Wh,
    const float* __restrict__ gtb, const float* __restrict__ outb,
    float* __restrict__ outp)
{
  __shared__ char smem[53248];
  unsigned short* vs = reinterpret_cast<unsigned short*>(smem);        // [128][72] fp16
  char* zgb = smem + 18432;
  char* zvb = smem + 36864;
  const int t  = threadIdx.x;
  const int p0 = blockIdx.x * 64;

#pragma unroll
  for (int q = 0; q < 4; ++q) {
    int ci = t + 256 * q;
    int c = ci >> 3, ch8 = ci & 7;
    uint4 u = *reinterpret_cast<const uint4*>(v16 + (size_t)c * NN + p0 + ch8 * 8);
    int g = ch8 ^ (c & 7);
    *reinterpret_cast<uint4*>(vs + c * 72 + g * 8) = u;
  }
  {
    const int rl = t >> 2, quad = t & 3, c0 = quad * 32;
    const float4* src = reinterpret_cast<const float4*>(pair + (size_t)(p0 + rl) * CZC + c0);
    float v[32];
    float s = 0.f, ss = 0.f;
#pragma unroll
    for (int q = 0; q < 8; ++q) {
      float4 f4 = src[q];
      v[4*q] = f4.x; v[4*q+1] = f4.y; v[4*q+2] = f4.z; v[4*q+3] = f4.w;
    }
#pragma unroll
    for (int j = 0; j < 32; ++j) { s += v[j]; ss += v[j] * v[j]; }
    s  += __shfl_xor(s, 1);  s  += __shfl_xor(s, 2);
    ss += __shfl_xor(ss, 1); ss += __shfl_xor(ss, 2);
    const float mu   = s * (1.f / 128.f);
    const float rstd = rsqrtf(ss * (1.f / 128.f) - mu * mu + 1e-5f);
    unsigned u[16];
#pragma unroll
    for (int q = 0; q < 8; ++q) {
      float4 w4 = reinterpret_cast<const float4*>(lnpw + c0)[q];
      float4 b4 = reinterpret_cast<const float4*>(lnpb + c0)[q];
      float z0 = (v[4*q  ] - mu) * rstd * w4.x + b4.x;
      float z1 = (v[4*q+1] - mu) * rstd * w4.y + b4.y;
      float z2 = (v[4*q+2] - mu) * rstd * w4.z + b4.z;
      float z3 = (v[4*q+3] - mu) * rstd * w4.w + b4.w;
      u[2*q] = pk2(z0, z1); u[2*q+1] = pk2(z2, z3);
    }
#pragma unroll
    for (int g = 0; g < 4; ++g) {
      int gi = quad * 4 + g;
      *reinterpret_cast<uint4*>(zgb + rl * 256 + 16 * (gi ^ (rl & 7))) =
          make_uint4(u[4*g], u[4*g+1], u[4*g+2], u[4*g+3]);
    }
  }
  __syncthreads();

  const int w = t >> 6, l = t & 63;
  const int lrow = l & 15, lk = l >> 4;
  const int colbase = w * 32;

  auto ldZ = [&](const char* base, int mt, int ks) -> f16x8 {
    int row = mt * 16 + lrow;
    int gi  = ks * 4 + lk;
    return *reinterpret_cast<const f16x8*>(base + row * 256 + 16 * (gi ^ (row & 7)));
  };
  auto ldW = [&](const unsigned short* Wm, int nt, int ks) -> f16x8 {
    int cz = colbase + nt * 16 + lrow;
    return *reinterpret_cast<const f16x8*>(Wm + cz * 128 + ks * 32 + lk * 8);
  };

  f32x4 gacc[4][2];
#pragma unroll
  for (int mt = 0; mt < 4; ++mt)
#pragma unroll
    for (int nt = 0; nt < 2; ++nt) gacc[mt][nt] = 0.f;
  {
    const unsigned short* Wg = Wh + 4 * 16384;
#pragma unroll
    for (int ks = 0; ks < 4; ++ks) {
      f16x8 af[4];
#pragma unroll
      for (int mt = 0; mt < 4; ++mt) af[mt] = ldZ(zgb, mt, ks);
#pragma unroll
      for (int nt = 0; nt < 2; ++nt) {
        f16x8 bf_ = ldW(Wg, nt, ks);
#pragma unroll
        for (int mt = 0; mt < 4; ++mt)
          gacc[mt][nt] = __builtin_amdgcn_mfma_f32_16x16x32_f16(af[mt], bf_, gacc[mt][nt], 0, 0, 0);
      }
    }
  }

  {
    const int pl = t >> 2, quad = t & 3, c0q = quad * 32;
    float v[32];
#pragma unroll
    for (int j = 0; j < 32; ++j) {
      int c = c0q + j;
      v[j] = h2f(vs[c * 72 + (((pl >> 3) ^ (c & 7)) << 3) + (pl & 7)]);
    }
    float s = 0.f, ss = 0.f;
#pragma unroll
    for (int j = 0; j < 32; ++j) { s += v[j]; ss += v[j] * v[j]; }
    s  += __shfl_xor(s, 1);  s  += __shfl_xor(s, 2);
    ss += __shfl_xor(ss, 1); ss += __shfl_xor(ss, 2);
    const float mu   = s * (1.f / 128.f);
    const float rstd = rsqrtf(ss * (1.f / 128.f) - mu * mu + 1e-5f);
    unsigned u[16];
#pragma unroll
    for (int q = 0; q < 8; ++q) {
      float4 w4 = reinterpret_cast<const float4*>(lnow + c0q)[q];
      float4 b4 = reinterpret_cast<const float4*>(lnob + c0q)[q];
      float z0 = (v[4*q  ] - mu) * rstd * w4.x + b4.x;
      float z1 = (v[4*q+1] - mu) * rstd * w4.y + b4.y;
      float z2 = (v[4*q+2] - mu) * rstd * w4.z + b4.z;
      float z3 = (v[4*q+3] - mu) * rstd * w4.w + b4.w;
      u[2*q] = pk2(z0, z1); u[2*q+1] = pk2(z2, z3);
    }
#pragma unroll
    for (int g = 0; g < 4; ++g) {
      int gi = quad * 4 + g;
      *reinterpret_cast<uint4*>(zvb + pl * 256 + 16 * (gi ^ (pl & 7))) =
          make_uint4(u[4*g], u[4*g+1], u[4*g+2], u[4*g+3]);
    }
  }
  __syncthreads();

  const unsigned short* Wo = Wh + 5 * 16384;
  f32x4 acc[4][2];
#pragma unroll
  for (int mt = 0; mt < 4; ++mt)
#pragma unroll
    for (int nt = 0; nt < 2; ++nt) acc[mt][nt] = 0.f;
#pragma unroll
  for (int ks = 0; ks < 4; ++ks) {
    f16x8 af[4];
#pragma unroll
    for (int mt = 0; mt < 4; ++mt) af[mt] = ldZ(zvb, mt, ks);
#pragma unroll
    for (int nt = 0; nt < 2; ++nt) {
      f16x8 bf_ = ldW(Wo, nt, ks);
#pragma unroll
      for (int mt = 0; mt < 4; ++mt)
        acc[mt][nt] = __builtin_amdgcn_mfma_f32_16x16x32_f16(af[mt], bf_, acc[mt][nt], 0, 0, 0);
    }
  }
#pragma unroll
  for (int mt = 0; mt < 4; ++mt)
#pragma unroll
    for (int nt = 0; nt < 2; ++nt) {
      int cz = colbase + nt * 16 + lrow;
      float ob = outb[cz], gb = gtb[cz];
#pragma unroll
      for (int reg = 0; reg < 4; ++reg) {
        int plc = mt * 16 + lk * 4 + reg;
        float gv = sigmoidf_(gacc[mt][nt][reg] + gb);
        outp[(size_t)(p0 + plc) * CZC + cz] = gv * (acc[mt][nt][reg] + ob);
      }
    }
}

// ---------------------------------------------------------------- launch
// ws   : Wh (196608 B) | V fp16 [128][NN] | G fp16 strip (if ws fits)
// d_out: A fp16 strip [0,H), B fp16 strip [H,2H) during k1/k2; k3 overwrites with output.
extern "C" void kernel_launch(void* const* d_in, const int* in_sizes, int n_in,
                              void* d_out, int out_size, void* d_ws, size_t ws_size,
                              hipStream_t stream)
{
  const float* pair      = (const float*)d_in[0];
  const float* ln_pair_w = (const float*)d_in[1];
  const float* ln_pair_b = (const float*)d_in[2];
  const float* ln_out_w  = (const float*)d_in[3];
  const float* ln_out_b  = (const float*)d_in[4];
  const float* g1_w      = (const float*)d_in[5];
  const float* g1_b      = (const float*)d_in[6];
  const float* g2_w      = (const float*)d_in[7];
  const float* g2_b      = (const float*)d_in[8];
  const float* l1_w      = (const float*)d_in[9];
  const float* l1_b      = (const float*)d_in[10];
  const float* l2_w      = (const float*)d_in[11];
  const float* l2_b      = (const float*)d_in[12];
  const float* gate_w    = (const float*)d_in[13];
  const float* gate_b    = (const float*)d_in[14];
  const float* out_w     = (const float*)d_in[15];
  const float* out_b     = (const float*)d_in[16];

  const size_t WH = 196608;
  const size_t H  = 37748736;
  char* ws  = (char*)d_ws;
  char* dob = (char*)d_out;

  unsigned short* Wp = (unsigned short*)ws;
  unsigned short* V  = (unsigned short*)(ws + WH);
  unsigned short* G  = (ws_size >= WH + 2 * H) ? (unsigned short*)(ws + WH + H) : nullptr;
  unsigned short* Ah = (unsigned short*)dob;        // [0, H)
  unsigned short* Bh = (unsigned short*)(dob + H);  // [H, 2H)

  k0_conv<<<384, 256, 0, stream>>>(g1_w, l1_w, g2_w, l2_w, gate_w, out_w, Wp);
  k1_proj<<<1152, 256, 0, stream>>>(pair, ln_pair_w, ln_pair_b, Wp,
                                    g1_b, l1_b, g2_b, l2_b, gate_b, Ah, Bh, G);
  k2_tri<<<1152, 256, 0, stream>>>(Ah, Bh, V);
  if (G)
    k3g<<<2304, 256, 0, stream>>>(V, G, ln_out_w, ln_out_b, Wp, out_b, (float*)d_out);
  else
    k3r<<<2304, 256, 0, stream>>>(pair, V, ln_pair_w, ln_pair_b, ln_out_w, ln_out_b,
                                  Wp, gate_b, out_b, (float*)d_out);
}

// Round 19
// 153.129 us; speedup vs baseline: 2.0400x; 2.0400x over previous
//
#include <hip/hip_runtime.h>
#include <hip/hip_fp16.h>

#define NDIM 384
#define NN   147456    // 384*384
#define CZC  128

typedef _Float16 f16x8 __attribute__((ext_vector_type(8)));
typedef float    f32x4 __attribute__((ext_vector_type(4)));

static __device__ __forceinline__ unsigned short f2h(float f) {
  return __builtin_bit_cast(unsigned short, __float2half(f));
}
static __device__ __forceinline__ float h2f(unsigned short s) {
  return __half2float(__builtin_bit_cast(__half, s));
}
static __device__ __forceinline__ unsigned pk2(float lo, float hi) {
  return (unsigned)f2h(lo) | ((unsigned)f2h(hi) << 16);
}
// fast sigmoid: v_exp + v_rcp (1 ulp)
static __device__ __forceinline__ float sigmoidf_(float x) {
  return __builtin_amdgcn_rcpf(1.0f + __expf(-x));
}

// A/B/G strip layout: X[(i*128 + c)*384 + k]  (i = pair-row, c = channel, k = pair-col)

// ---------------------------------------------------------------- k0: weights fp32 -> fp16
__global__ void k0_conv(const float* __restrict__ g1, const float* __restrict__ l1,
                        const float* __restrict__ g2, const float* __restrict__ l2,
                        const float* __restrict__ gw, const float* __restrict__ ow,
                        unsigned short* __restrict__ Wh)
{
  const int m = blockIdx.x >> 6;
  const float* s = (m == 0) ? g1 : (m == 1) ? l1 : (m == 2) ? g2 : (m == 3) ? l2
                 : (m == 4) ? gw : ow;
  const int e = (blockIdx.x & 63) * 256 + threadIdx.x;
  Wh[m * 16384 + e] = f2h(s[e]);
}

// ---------------------------------------------------------------- k1: LN + A/B/G projections
// Best-measured config (R11/R15, 87.7us): 256 thr, 128 pts/block, grid 1152, 2 blocks/CU,
// staged LDS flush with 256B contiguous segments (direct 8B stores amplify writes 4.4x — R18).
__global__ __launch_bounds__(256, 2) void k1_proj(
    const float* __restrict__ pair, const float* __restrict__ lnw, const float* __restrict__ lnb,
    const unsigned short* __restrict__ Wh,
    const float* __restrict__ g1b, const float* __restrict__ l1b,
    const float* __restrict__ g2b, const float* __restrict__ l2b,
    const float* __restrict__ gtb,
    unsigned short* __restrict__ Ah, unsigned short* __restrict__ Bh,
    unsigned short* __restrict__ G)     // may be null (ws too small)
{
  __shared__ char zb[32768];   // z fp16 [128 rows][128c], 256B/row, 16B-granule XOR (row&7)
  __shared__ char sb[32768];   // store-stage [128 col][128 pts], 256B/col, 16B-granule XOR (col&15)
  const int t   = threadIdx.x;
  const int xcd = blockIdx.x & 7;
  const int r0  = (xcd * 144 + (blockIdx.x >> 3)) * 128;  // XCD-contiguous point ranges
  const int irow = r0 / NDIM;          // fixed pair-row for this block
  const int kk0  = r0 % NDIM;          // k-third: 0 / 128 / 256

  { // ---- load + LN -> z fp16 in LDS (4 lanes per row, 2 batches of 64 rows)
    const int rl = t >> 2, quad = t & 3, c0 = quad * 32;
    for (int b = 0; b < 2; ++b) {
      const int row = b * 64 + rl;
      const float4* src = reinterpret_cast<const float4*>(pair + (size_t)(r0 + row) * CZC + c0);
      float v[32];
      float s = 0.f, ss = 0.f;
#pragma unroll
      for (int q = 0; q < 8; ++q) {
        float4 f4 = src[q];
        v[4*q] = f4.x; v[4*q+1] = f4.y; v[4*q+2] = f4.z; v[4*q+3] = f4.w;
      }
#pragma unroll
      for (int j = 0; j < 32; ++j) { s += v[j]; ss += v[j] * v[j]; }
      s  += __shfl_xor(s, 1);  s  += __shfl_xor(s, 2);
      ss += __shfl_xor(ss, 1); ss += __shfl_xor(ss, 2);
      const float mu   = s * (1.f / 128.f);
      const float rstd = rsqrtf(ss * (1.f / 128.f) - mu * mu + 1e-5f);
      unsigned u[16];
#pragma unroll
      for (int q = 0; q < 8; ++q) {
        float4 w4 = reinterpret_cast<const float4*>(lnw + c0)[q];
        float4 b4 = reinterpret_cast<const float4*>(lnb + c0)[q];
        float z0 = (v[4*q  ] - mu) * rstd * w4.x + b4.x;
        float z1 = (v[4*q+1] - mu) * rstd * w4.y + b4.y;
        float z2 = (v[4*q+2] - mu) * rstd * w4.z + b4.z;
        float z3 = (v[4*q+3] - mu) * rstd * w4.w + b4.w;
        u[2*q] = pk2(z0, z1); u[2*q+1] = pk2(z2, z3);
      }
#pragma unroll
      for (int g = 0; g < 4; ++g) {
        int gi = quad * 4 + g;
        *reinterpret_cast<uint4*>(zb + row * 256 + 16 * (gi ^ (row & 7))) =
            make_uint4(u[4*g], u[4*g+1], u[4*g+2], u[4*g+3]);
      }
    }
  }
  __syncthreads();

  const int w = t >> 6, l = t & 63;
  const int lrow = l & 15, lk = l >> 4;
  const int colbase = w * 32;

  auto ldA = [&](int h, int mt, int ks) -> f16x8 {
    int row = h * 64 + mt * 16 + lrow;
    int gi  = ks * 4 + lk;
    return *reinterpret_cast<const f16x8*>(zb + row * 256 + 16 * (gi ^ (row & 7)));
  };
  auto ldB = [&](const unsigned short* Wm, int nt, int ks) -> f16x8 {
    int col = colbase + nt * 16 + lrow;
    return *reinterpret_cast<const f16x8*>(Wm + col * 128 + ks * 32 + lk * 8);
  };
  // stage one uint2 (4 pts) at (col, point h*64 + mt*16 + lk*4)
  auto stageh = [&](int col, int h, int mt, unsigned lo, unsigned hi) {
    int gran = h * 8 + mt * 2 + (lk >> 1);          // 16B granule = point>>3
    *reinterpret_cast<uint2*>(sb + col * 256 + 16 * (gran ^ (col & 15)) + (lk & 1) * 8)
        = make_uint2(lo, hi);
  };
  // strip-layout store: channel cl's 256B goes to (irow*128+cl)*384 + kk0 (+sl*8)
  auto flush = [&](unsigned short* Ot) {
    unsigned short* base = Ot + (size_t)irow * 128 * NDIM + kk0;
#pragma unroll
    for (int q = 0; q < 8; ++q) {
      int i = t + 256 * q;              // 2048 chunks of 16B
      int cl = i >> 4, sl = i & 15;
      uint4 u = *reinterpret_cast<const uint4*>(sb + cl * 256 + 16 * (sl ^ (cl & 15)));
      *reinterpret_cast<uint4*>(base + (size_t)cl * NDIM + sl * 8) = u;
    }
  };

  auto do_pair = [&](const unsigned short* Wg, const unsigned short* Wl,
                     const float* bgp, const float* blp, unsigned short* Ot) {
    __syncthreads();                    // sb free (previous flush reads done)
#pragma unroll
    for (int h = 0; h < 2; ++h) {
      f32x4 accg[4][2], accl[4][2];
#pragma unroll
      for (int mt = 0; mt < 4; ++mt)
#pragma unroll
        for (int nt = 0; nt < 2; ++nt) { accg[mt][nt] = 0.f; accl[mt][nt] = 0.f; }
#pragma unroll
      for (int ks = 0; ks < 4; ++ks) {
        f16x8 af[4];
#pragma unroll
        for (int mt = 0; mt < 4; ++mt) af[mt] = ldA(h, mt, ks);
#pragma unroll
        for (int nt = 0; nt < 2; ++nt) {
          f16x8 bg_ = ldB(Wg, nt, ks);
#pragma unroll
          for (int mt = 0; mt < 4; ++mt)
            accg[mt][nt] = __builtin_amdgcn_mfma_f32_16x16x32_f16(af[mt], bg_, accg[mt][nt], 0, 0, 0);
          f16x8 bl_ = ldB(Wl, nt, ks);
#pragma unroll
          for (int mt = 0; mt < 4; ++mt)
            accl[mt][nt] = __builtin_amdgcn_mfma_f32_16x16x32_f16(af[mt], bl_, accl[mt][nt], 0, 0, 0);
        }
      }
#pragma unroll
      for (int mt = 0; mt < 4; ++mt)
#pragma unroll
        for (int nt = 0; nt < 2; ++nt) {
          int col = colbase + nt * 16 + lrow;
          float gb = bgp[col], lb = blp[col];
          float a0 = sigmoidf_(accg[mt][nt][0] + gb) * (accl[mt][nt][0] + lb);
          float a1 = sigmoidf_(accg[mt][nt][1] + gb) * (accl[mt][nt][1] + lb);
          float a2 = sigmoidf_(accg[mt][nt][2] + gb) * (accl[mt][nt][2] + lb);
          float a3 = sigmoidf_(accg[mt][nt][3] + gb) * (accl[mt][nt][3] + lb);
          stageh(col, h, mt, pk2(a0, a1), pk2(a2, a3));
        }
    }
    __syncthreads();
    flush(Ot);
  };

  do_pair(Wh + 0 * 16384, Wh + 1 * 16384, g1b, l1b, Ah);
  do_pair(Wh + 2 * 16384, Wh + 3 * 16384, g2b, l2b, Bh);

  if (G) {  // gate -> G strip-layout
    __syncthreads();
    const unsigned short* Wg = Wh + 4 * 16384;
#pragma unroll
    for (int h = 0; h < 2; ++h) {
      f32x4 acc[4][2];
#pragma unroll
      for (int mt = 0; mt < 4; ++mt)
#pragma unroll
        for (int nt = 0; nt < 2; ++nt) acc[mt][nt] = 0.f;
#pragma unroll
      for (int ks = 0; ks < 4; ++ks) {
        f16x8 af[4];
#pragma unroll
        for (int mt = 0; mt < 4; ++mt) af[mt] = ldA(h, mt, ks);
#pragma unroll
        for (int nt = 0; nt < 2; ++nt) {
          f16x8 bf_ = ldB(Wg, nt, ks);
#pragma unroll
          for (int mt = 0; mt < 4; ++mt)
            acc[mt][nt] = __builtin_amdgcn_mfma_f32_16x16x32_f16(af[mt], bf_, acc[mt][nt], 0, 0, 0);
        }
      }
#pragma unroll
      for (int mt = 0; mt < 4; ++mt)
#pragma unroll
        for (int nt = 0; nt < 2; ++nt) {
          int col = colbase + nt * 16 + lrow;
          float gb = gtb[col];
          stageh(col, h, mt,
                 pk2(sigmoidf_(acc[mt][nt][0] + gb), sigmoidf_(acc[mt][nt][1] + gb)),
                 pk2(sigmoidf_(acc[mt][nt][2] + gb), sigmoidf_(acc[mt][nt][3] + gb)));
        }
    }
    __syncthreads();
    flush(G);
  }
}

// ---------------------------------------------------------------- k2: per-channel NT GEMM
// V16[c][i][j] = sum_k A[i][c][k]*B[j][c][k] (strip layout inputs). 128x128 tile, BK=32.
// XCD swizzle keeps a channel's 9 tiles on one XCD. V stays channel-major [c][i][j].
__global__ __launch_bounds__(256) void k2_tri(
    const unsigned short* __restrict__ Ah, const unsigned short* __restrict__ Bh,
    unsigned short* __restrict__ v16)
{
  __shared__ char As[8192];   // [128 rows][32 k] fp16, 64B/row, granule XOR (row&3)
  __shared__ char Bs[8192];
  __shared__ char Vs[32768];  // store-stage [128 i][128 j] fp16, 256B/row, 16B-slot XOR (i&15)
  const int x  = blockIdx.x & 7;
  const int r  = blockIdx.x >> 3;
  const int tt = r % 9;
  const int c  = (r / 9) * 8 + x;
  const int ib = (tt / 3) * 128, jb = (tt % 3) * 128;
  const size_t co = (size_t)c * NN;
  const int t = threadIdx.x, w = t >> 6, l = t & 63;
  const int wi = (w >> 1) * 64, wj = (w & 1) * 64;
  const int lrow = l & 15, lk = l >> 4;
  const int srow = t >> 2, sgr = t & 3;

  f32x4 acc[4][4];
#pragma unroll
  for (int mt = 0; mt < 4; ++mt)
#pragma unroll
    for (int nt = 0; nt < 4; ++nt) acc[mt][nt] = 0.f;

  for (int kb = 0; kb < 12; ++kb) {
    // strip layout: element (row, c, k) at (row*128 + c)*384 + k
    const int kofs = kb * 32 + sgr * 8;
    const size_t ka  = ((size_t)(ib + srow) * 128 + c) * NDIM + kofs;
    const size_t kb_ = ((size_t)(jb + srow) * 128 + c) * NDIM + kofs;
    const size_t rstep = (size_t)64 * 128 * NDIM;
    uint4 a0 = *reinterpret_cast<const uint4*>(Ah + ka);
    uint4 a1 = *reinterpret_cast<const uint4*>(Ah + ka + rstep);
    uint4 b0 = *reinterpret_cast<const uint4*>(Bh + kb_);
    uint4 b1 = *reinterpret_cast<const uint4*>(Bh + kb_ + rstep);
    __syncthreads();
    const int g0 = 16 * (sgr ^ (srow & 3));
    *reinterpret_cast<uint4*>(As + srow * 64 + g0)        = a0;
    *reinterpret_cast<uint4*>(As + (srow + 64) * 64 + g0) = a1;
    *reinterpret_cast<uint4*>(Bs + srow * 64 + g0)        = b0;
    *reinterpret_cast<uint4*>(Bs + (srow + 64) * 64 + g0) = b1;
    __syncthreads();
    f16x8 af[4], bfr[4];
#pragma unroll
    for (int mt = 0; mt < 4; ++mt) {
      int row = wi + mt * 16 + lrow;
      af[mt] = *reinterpret_cast<const f16x8*>(As + row * 64 + 16 * (lk ^ (row & 3)));
    }
#pragma unroll
    for (int nt = 0; nt < 4; ++nt) {
      int row = wj + nt * 16 + lrow;
      bfr[nt] = *reinterpret_cast<const f16x8*>(Bs + row * 64 + 16 * (lk ^ (row & 3)));
    }
#pragma unroll
    for (int mt = 0; mt < 4; ++mt)
#pragma unroll
      for (int nt = 0; nt < 4; ++nt)
        acc[mt][nt] = __builtin_amdgcn_mfma_f32_16x16x32_f16(af[mt], bfr[nt], acc[mt][nt], 0, 0, 0);
  }

  // ---- stage V tile [i][j] then coalesced 256B-row stores
  __syncthreads();
#pragma unroll
  for (int mt = 0; mt < 4; ++mt)
#pragma unroll
    for (int nt = 0; nt < 4; ++nt) {
      const int j = wj + nt * 16 + lrow;
#pragma unroll
      for (int reg = 0; reg < 4; ++reg) {
        const int i = wi + mt * 16 + lk * 4 + reg;
        int sl = (j >> 3) ^ (i & 15);
        *reinterpret_cast<unsigned short*>(Vs + i * 256 + sl * 16 + (j & 7) * 2)
            = f2h(acc[mt][nt][reg]);
      }
    }
  __syncthreads();
  unsigned short* vc = v16 + co;
#pragma unroll
  for (int q = 0; q < 8; ++q) {
    int idx = t + 256 * q;              // 2048 chunks of 16B
    int i = idx >> 4, sl = idx & 15;
    uint4 u = *reinterpret_cast<const uint4*>(Vs + i * 256 + ((sl ^ (i & 15)) * 16));
    *reinterpret_cast<uint4*>(vc + (size_t)(ib + i) * NDIM + jb + sl * 8) = u;
  }
}

// ---------------------------------------------------------------- k3g: LN(vals) @ out_w^T * G + out_b
// G-materialized tier. G read from strip layout. zvb overlays vs after barrier.
__global__ __launch_bounds__(256, 4) void k3g(
    const unsigned short* __restrict__ v16, const unsigned short* __restrict__ G,
    const float* __restrict__ lnow, const float* __restrict__ lnob,
    const unsigned short* __restrict__ Wh, const float* __restrict__ outb,
    float* __restrict__ outp)
{
  __shared__ char smem[36864];
  unsigned short* vs = reinterpret_cast<unsigned short*>(smem);        // [128][72] fp16
  unsigned short* gs = reinterpret_cast<unsigned short*>(smem + 18432);
  char* zvb = smem;                    // overlays vs after its reads complete
  const int t  = threadIdx.x;
  const int p0 = blockIdx.x * 64;
  const int irow = p0 / NDIM;          // fixed pair-row (64 | 384)
  const int kk0  = p0 % NDIM;

  // ---- phase A: V (channel-major) + G (strip) tiles -> LDS
#pragma unroll
  for (int q = 0; q < 4; ++q) {
    int ci = t + 256 * q;
    int c = ci >> 3, ch8 = ci & 7;
    uint4 u = *reinterpret_cast<const uint4*>(v16 + (size_t)c * NN + p0 + ch8 * 8);
    int g = ch8 ^ (c & 7);
    *reinterpret_cast<uint4*>(vs + c * 72 + g * 8) = u;
  }
  {
    const unsigned short* gbase = G + (size_t)irow * 128 * NDIM + kk0;
#pragma unroll
    for (int q = 0; q < 4; ++q) {
      int ci = t + 256 * q;
      int c = ci >> 3, ch8 = ci & 7;
      uint4 u = *reinterpret_cast<const uint4*>(gbase + (size_t)c * NDIM + ch8 * 8);
      int g = ch8 ^ (c & 7);
      *reinterpret_cast<uint4*>(gs + c * 72 + g * 8) = u;
    }
  }
  __syncthreads();

  const int w = t >> 6, l = t & 63;
  const int lrow = l & 15, lk = l >> 4;
  const int colbase = w * 32;

  { // ---- phase C: per-point LN(vals) -> zvb (overlaid on vs)
    const int pl = t >> 2, quad = t & 3, c0q = quad * 32;
    float v[32];
#pragma unroll
    for (int j = 0; j < 32; ++j) {
      int c = c0q + j;
      v[j] = h2f(vs[c * 72 + (((pl >> 3) ^ (c & 7)) << 3) + (pl & 7)]);
    }
    float s = 0.f, ss = 0.f;
#pragma unroll
    for (int j = 0; j < 32; ++j) { s += v[j]; ss += v[j] * v[j]; }
    s  += __shfl_xor(s, 1);  s  += __shfl_xor(s, 2);
    ss += __shfl_xor(ss, 1); ss += __shfl_xor(ss, 2);
    const float mu   = s * (1.f / 128.f);
    const float rstd = rsqrtf(ss * (1.f / 128.f) - mu * mu + 1e-5f);
    unsigned u[16];
#pragma unroll
    for (int q = 0; q < 8; ++q) {
      float4 w4 = reinterpret_cast<const float4*>(lnow + c0q)[q];
      float4 b4 = reinterpret_cast<const float4*>(lnob + c0q)[q];
      float z0 = (v[4*q  ] - mu) * rstd * w4.x + b4.x;
      float z1 = (v[4*q+1] - mu) * rstd * w4.y + b4.y;
      float z2 = (v[4*q+2] - mu) * rstd * w4.z + b4.z;
      float z3 = (v[4*q+3] - mu) * rstd * w4.w + b4.w;
      u[2*q] = pk2(z0, z1); u[2*q+1] = pk2(z2, z3);
    }
    __syncthreads();                   // all vs reads complete before overwrite
#pragma unroll
    for (int g = 0; g < 4; ++g) {
      int gi = quad * 4 + g;
      *reinterpret_cast<uint4*>(zvb + pl * 256 + 16 * (gi ^ (pl & 7))) =
          make_uint4(u[4*g], u[4*g+1], u[4*g+2], u[4*g+3]);
    }
  }
  __syncthreads();

  // ---- phase D: out MFMA + gated epilogue
  const unsigned short* Wo = Wh + 5 * 16384;
  f32x4 acc[4][2];
#pragma unroll
  for (int mt = 0; mt < 4; ++mt)
#pragma unroll
    for (int nt = 0; nt < 2; ++nt) acc[mt][nt] = 0.f;
#pragma unroll
  for (int ks = 0; ks < 4; ++ks) {
    f16x8 af[4];
#pragma unroll
    for (int mt = 0; mt < 4; ++mt) {
      int row = mt * 16 + lrow;
      int gi  = ks * 4 + lk;
      af[mt] = *reinterpret_cast<const f16x8*>(zvb + row * 256 + 16 * (gi ^ (row & 7)));
    }
#pragma unroll
    for (int nt = 0; nt < 2; ++nt) {
      int cz = colbase + nt * 16 + lrow;
      f16x8 bf_ = *reinterpret_cast<const f16x8*>(Wo + cz * 128 + ks * 32 + lk * 8);
#pragma unroll
      for (int mt = 0; mt < 4; ++mt)
        acc[mt][nt] = __builtin_amdgcn_mfma_f32_16x16x32_f16(af[mt], bf_, acc[mt][nt], 0, 0, 0);
    }
  }
#pragma unroll
  for (int mt = 0; mt < 4; ++mt)
#pragma unroll
    for (int nt = 0; nt < 2; ++nt) {
      int cz = colbase + nt * 16 + lrow;
      float ob = outb[cz];
#pragma unroll
      for (int reg = 0; reg < 4; ++reg) {
        int plc = mt * 16 + lk * 4 + reg;
        float gv = h2f(gs[cz * 72 + (((plc >> 3) ^ (cz & 7)) << 3) + (plc & 7)]);
        outp[(size_t)(p0 + plc) * CZC + cz] = gv * (acc[mt][nt][reg] + ob);
      }
    }
}

// ---------------------------------------------------------------- k3r: recompute-gate tier (no G)
__global__ __launch_bounds__(256, 3) void k3r(
    const float* __restrict__ pair, const unsigned short* __restrict__ v16,
    const float* __restrict__ lnpw, const float* __restrict__ lnpb,
    const float* __restrict__ lnow, const float* __restrict__ lnob,
    const unsigned short* __restrict__ Wh,
    const float* __restrict__ gtb, const float* __restrict__ outb,
    float* __restrict__ outp)
{
  __shared__ char smem[53248];
  unsigned short* vs = reinterpret_cast<unsigned short*>(smem);        // [128][72] fp16
  char* zgb = smem + 18432;
  char* zvb = smem + 36864;
  const int t  = threadIdx.x;
  const int p0 = blockIdx.x * 64;

#pragma unroll
  for (int q = 0; q < 4; ++q) {
    int ci = t + 256 * q;
    int c = ci >> 3, ch8 = ci & 7;
    uint4 u = *reinterpret_cast<const uint4*>(v16 + (size_t)c * NN + p0 + ch8 * 8);
    int g = ch8 ^ (c & 7);
    *reinterpret_cast<uint4*>(vs + c * 72 + g * 8) = u;
  }
  {
    const int rl = t >> 2, quad = t & 3, c0 = quad * 32;
    const float4* src = reinterpret_cast<const float4*>(pair + (size_t)(p0 + rl) * CZC + c0);
    float v[32];
    float s = 0.f, ss = 0.f;
#pragma unroll
    for (int q = 0; q < 8; ++q) {
      float4 f4 = src[q];
      v[4*q] = f4.x; v[4*q+1] = f4.y; v[4*q+2] = f4.z; v[4*q+3] = f4.w;
    }
#pragma unroll
    for (int j = 0; j < 32; ++j) { s += v[j]; ss += v[j] * v[j]; }
    s  += __shfl_xor(s, 1);  s  += __shfl_xor(s, 2);
    ss += __shfl_xor(ss, 1); ss += __shfl_xor(ss, 2);
    const float mu   = s * (1.f / 128.f);
    const float rstd = rsqrtf(ss * (1.f / 128.f) - mu * mu + 1e-5f);
    unsigned u[16];
#pragma unroll
    for (int q = 0; q < 8; ++q) {
      float4 w4 = reinterpret_cast<const float4*>(lnpw + c0)[q];
      float4 b4 = reinterpret_cast<const float4*>(lnpb + c0)[q];
      float z0 = (v[4*q  ] - mu) * rstd * w4.x + b4.x;
      float z1 = (v[4*q+1] - mu) * rstd * w4.y + b4.y;
      float z2 = (v[4*q+2] - mu) * rstd * w4.z + b4.z;
      float z3 = (v[4*q+3] - mu) * rstd * w4.w + b4.w;
      u[2*q] = pk2(z0, z1); u[2*q+1] = pk2(z2, z3);
    }
#pragma unroll
    for (int g = 0; g < 4; ++g) {
      int gi = quad * 4 + g;
      *reinterpret_cast<uint4*>(zgb + rl * 256 + 16 * (gi ^ (rl & 7))) =
          make_uint4(u[4*g], u[4*g+1], u[4*g+2], u[4*g+3]);
    }
  }
  __syncthreads();

  const int w = t >> 6, l = t & 63;
  const int lrow = l & 15, lk = l >> 4;
  const int colbase = w * 32;

  auto ldZ = [&](const char* base, int mt, int ks) -> f16x8 {
    int row = mt * 16 + lrow;
    int gi  = ks * 4 + lk;
    return *reinterpret_cast<const f16x8*>(base + row * 256 + 16 * (gi ^ (row & 7)));
  };
  auto ldW = [&](const unsigned short* Wm, int nt, int ks) -> f16x8 {
    int cz = colbase + nt * 16 + lrow;
    return *reinterpret_cast<const f16x8*>(Wm + cz * 128 + ks * 32 + lk * 8);
  };

  f32x4 gacc[4][2];
#pragma unroll
  for (int mt = 0; mt < 4; ++mt)
#pragma unroll
    for (int nt = 0; nt < 2; ++nt) gacc[mt][nt] = 0.f;
  {
    const unsigned short* Wg = Wh + 4 * 16384;
#pragma unroll
    for (int ks = 0; ks < 4; ++ks) {
      f16x8 af[4];
#pragma unroll
      for (int mt = 0; mt < 4; ++mt) af[mt] = ldZ(zgb, mt, ks);
#pragma unroll
      for (int nt = 0; nt < 2; ++nt) {
        f16x8 bf_ = ldW(Wg, nt, ks);
#pragma unroll
        for (int mt = 0; mt < 4; ++mt)
          gacc[mt][nt] = __builtin_amdgcn_mfma_f32_16x16x32_f16(af[mt], bf_, gacc[mt][nt], 0, 0, 0);
      }
    }
  }

  {
    const int pl = t >> 2, quad = t & 3, c0q = quad * 32;
    float v[32];
#pragma unroll
    for (int j = 0; j < 32; ++j) {
      int c = c0q + j;
      v[j] = h2f(vs[c * 72 + (((pl >> 3) ^ (c & 7)) << 3) + (pl & 7)]);
    }
    float s = 0.f, ss = 0.f;
#pragma unroll
    for (int j = 0; j < 32; ++j) { s += v[j]; ss += v[j] * v[j]; }
    s  += __shfl_xor(s, 1);  s  += __shfl_xor(s, 2);
    ss += __shfl_xor(ss, 1); ss += __shfl_xor(ss, 2);
    const float mu   = s * (1.f / 128.f);
    const float rstd = rsqrtf(ss * (1.f / 128.f) - mu * mu + 1e-5f);
    unsigned u[16];
#pragma unroll
    for (int q = 0; q < 8; ++q) {
      float4 w4 = reinterpret_cast<const float4*>(lnow + c0q)[q];
      float4 b4 = reinterpret_cast<const float4*>(lnob + c0q)[q];
      float z0 = (v[4*q  ] - mu) * rstd * w4.x + b4.x;
      float z1 = (v[4*q+1] - mu) * rstd * w4.y + b4.y;
      float z2 = (v[4*q+2] - mu) * rstd * w4.z + b4.z;
      float z3 = (v[4*q+3] - mu) * rstd * w4.w + b4.w;
      u[2*q] = pk2(z0, z1); u[2*q+1] = pk2(z2, z3);
    }
#pragma unroll
    for (int g = 0; g < 4; ++g) {
      int gi = quad * 4 + g;
      *reinterpret_cast<uint4*>(zvb + pl * 256 + 16 * (gi ^ (pl & 7))) =
          make_uint4(u[4*g], u[4*g+1], u[4*g+2], u[4*g+3]);
    }
  }
  __syncthreads();

  const unsigned short* Wo = Wh + 5 * 16384;
  f32x4 acc[4][2];
#pragma unroll
  for (int mt = 0; mt < 4; ++mt)
#pragma unroll
    for (int nt = 0; nt < 2; ++nt) acc[mt][nt] = 0.f;
#pragma unroll
  for (int ks = 0; ks < 4; ++ks) {
    f16x8 af[4];
#pragma unroll
    for (int mt = 0; mt < 4; ++mt) af[mt] = ldZ(zvb, mt, ks);
#pragma unroll
    for (int nt = 0; nt < 2; ++nt) {
      f16x8 bf_ = ldW(Wo, nt, ks);
#pragma unroll
      for (int mt = 0; mt < 4; ++mt)
        acc[mt][nt] = __builtin_amdgcn_mfma_f32_16x16x32_f16(af[mt], bf_, acc[mt][nt], 0, 0, 0);
    }
  }
#pragma unroll
  for (int mt = 0; mt < 4; ++mt)
#pragma unroll
    for (int nt = 0; nt < 2; ++nt) {
      int cz = colbase + nt * 16 + lrow;
      float ob = outb[cz], gb = gtb[cz];
#pragma unroll
      for (int reg = 0; reg < 4; ++reg) {
        int plc = mt * 16 + lk * 4 + reg;
        float gv = sigmoidf_(gacc[mt][nt][reg] + gb);
        outp[(size_t)(p0 + plc) * CZC + cz] = gv * (acc[mt][nt][reg] + ob);
      }
    }
}

// ---------------------------------------------------------------- launch
// ws   : Wh (196608 B) | V fp16 [128][NN] | G fp16 strip (if ws fits)
// d_out: A fp16 strip [0,H), B fp16 strip [H,2H) during k1/k2; k3 overwrites with output.
extern "C" void kernel_launch(void* const* d_in, const int* in_sizes, int n_in,
                              void* d_out, int out_size, void* d_ws, size_t ws_size,
                              hipStream_t stream)
{
  const float* pair      = (const float*)d_in[0];
  const float* ln_pair_w = (const float*)d_in[1];
  const float* ln_pair_b = (const float*)d_in[2];
  const float* ln_out_w  = (const float*)d_in[3];
  const float* ln_out_b  = (const float*)d_in[4];
  const float* g1_w      = (const float*)d_in[5];
  const float* g1_b      = (const float*)d_in[6];
  const float* g2_w      = (const float*)d_in[7];
  const float* g2_b      = (const float*)d_in[8];
  const float* l1_w      = (const float*)d_in[9];
  const float* l1_b      = (const float*)d_in[10];
  const float* l2_w      = (const float*)d_in[11];
  const float* l2_b      = (const float*)d_in[12];
  const float* gate_w    = (const float*)d_in[13];
  const float* gate_b    = (const float*)d_in[14];
  const float* out_w     = (const float*)d_in[15];
  const float* out_b     = (const float*)d_in[16];

  const size_t WH = 196608;
  const size_t H  = 37748736;
  char* ws  = (char*)d_ws;
  char* dob = (char*)d_out;

  unsigned short* Wp = (unsigned short*)ws;
  unsigned short* V  = (unsigned short*)(ws + WH);
  unsigned short* G  = (ws_size >= WH + 2 * H) ? (unsigned short*)(ws + WH + H) : nullptr;
  unsigned short* Ah = (unsigned short*)dob;        // [0, H)
  unsigned short* Bh = (unsigned short*)(dob + H);  // [H, 2H)

  k0_conv<<<384, 256, 0, stream>>>(g1_w, l1_w, g2_w, l2_w, gate_w, out_w, Wp);
  k1_proj<<<1152, 256, 0, stream>>>(pair, ln_pair_w, ln_pair_b, Wp,
                                    g1_b, l1_b, g2_b, l2_b, gate_b, Ah, Bh, G);
  k2_tri<<<1152, 256, 0, stream>>>(Ah, Bh, V);
  if (G)
    k3g<<<2304, 256, 0, stream>>>(V, G, ln_out_w, ln_out_b, Wp, out_b, (float*)d_out);
  else
    k3r<<<2304, 256, 0, stream>>>(pair, V, ln_pair_w, ln_pair_b, ln_out_w, ln_out_b,
                                  Wp, gate_b, out_b, (float*)d_out);
}